// Round 1
// baseline (229.640 us; speedup 1.0000x reference)
//
#include <hip/hip_runtime.h>
#include <stdint.h>

// Problem constants: t_q=64, t_k=128, b=32, n=1024
//   query (64,32,1024) f32 ; keys (128,32,1024) f32 ; Wq,Wk (1024,1024) f32
//   out0 = context (64,32,1024) f32 ; out1 = scores_softmax (64,32,128) f32
//
// Workspace layout (bytes), total ~40 MB:
//   v        @ 0        : 1025 f32 (v[1024] = sum(v))
//   pq       @ 8192     : 2048*1024 f32  (rows = t*32+b)
//   pk       @ +8MB     : 4096*1024 f32  (rows = k*32+b)
//   qb/kb/wqb/wkb       : bf16 copies of query/keys/Wq/Wk

typedef __attribute__((ext_vector_type(8))) short bf16x8;
typedef __attribute__((ext_vector_type(4))) float f32x4;

__device__ __forceinline__ unsigned short f2bf(float x) {
    union { float f; uint32_t u; } v; v.f = x;
    uint32_t u = v.u;
    u += 0x7fffu + ((u >> 16) & 1u);   // round-to-nearest-even
    return (unsigned short)(u >> 16);
}

__device__ __forceinline__ float wave_sum(float x) {
#pragma unroll
    for (int off = 32; off; off >>= 1) x += __shfl_xor(x, off);
    return x;
}
__device__ __forceinline__ float wave_max(float x) {
#pragma unroll
    for (int off = 32; off; off >>= 1) x = fmaxf(x, __shfl_xor(x, off));
    return x;
}

// ---------------- f32 -> bf16 conversion of all 4 tensors -------------------
__global__ __launch_bounds__(256) void convert_kernel(
    const float* __restrict__ q, const float* __restrict__ k,
    const float* __restrict__ wq, const float* __restrict__ wk,
    unsigned short* __restrict__ qb, unsigned short* __restrict__ kb,
    unsigned short* __restrict__ wqb, unsigned short* __restrict__ wkb) {
    int idx = blockIdx.x * 256 + threadIdx.x;   // float4 index; 2097152 total
    int e = idx * 4;
    const float* src; unsigned short* dst; int off;
    if (e < 2097152)      { src = q;  dst = qb;  off = e; }
    else if (e < 6291456) { src = k;  dst = kb;  off = e - 2097152; }
    else if (e < 7340032) { src = wq; dst = wqb; off = e - 6291456; }
    else                  { src = wk; dst = wkb; off = e - 7340032; }
    float4 xv = *(const float4*)(src + off);
    ushort4 o;
    o.x = f2bf(xv.x); o.y = f2bf(xv.y); o.z = f2bf(xv.z); o.w = f2bf(xv.w);
    *(ushort4*)(dst + off) = o;
}

// ---------------- v = linear_att/||linear_att|| * ns; also sum(v) -----------
__global__ __launch_bounds__(256) void vnorm_kernel(
    const float* __restrict__ la, const float* __restrict__ ns,
    float* __restrict__ v) {
    __shared__ float red[4], red2[4];
    int tid = threadIdx.x, w = tid >> 6;
    float s = 0.f;
    for (int i = tid; i < 1024; i += 256) { float x = la[i]; s += x * x; }
    s = wave_sum(s);
    if ((tid & 63) == 0) red[w] = s;
    __syncthreads();
    float scale = rsqrtf(red[0] + red[1] + red[2] + red[3]) * ns[0];
    float vp = 0.f;
    for (int i = tid; i < 1024; i += 256) { float vv = la[i] * scale; v[i] = vv; vp += vv; }
    vp = wave_sum(vp);
    if ((tid & 63) == 0) red2[w] = vp;
    __syncthreads();
    if (tid == 0) v[1024] = red2[0] + red2[1] + red2[2] + red2[3];
}

// ---------------- combined projection GEMM: C = A * B^T (bf16 -> f32) -------
// rows 0..2047   -> pq = qb * wqb^T
// rows 2048..6143-> pk = kb * wkb^T
// 128x128 block tile, 4 waves in 2x2, 64x64 per wave, mfma_f32_16x16x32_bf16.
__global__ __launch_bounds__(256) void proj_gemm(
    const unsigned short* __restrict__ qb, const unsigned short* __restrict__ kb,
    const unsigned short* __restrict__ wqb, const unsigned short* __restrict__ wkb,
    float* __restrict__ pq, float* __restrict__ pk) {
    int col0 = blockIdx.x * 128;
    int row0 = blockIdx.y * 128;
    const unsigned short* A; const unsigned short* Bm; float* C; int arow;
    if (row0 < 2048) { A = qb; Bm = wqb; C = pq; arow = row0; }
    else             { A = kb; Bm = wkb; C = pk; arow = row0 - 2048; }
    int tid = threadIdx.x;
    int w = tid >> 6, lane = tid & 63;
    int wm = w >> 1, wn = w & 1;
    int ml = lane & 15, quad = lane >> 4;

    const unsigned short* Abase = A + (arow + wm * 64 + ml) * 1024 + quad * 8;
    const unsigned short* Bbase = Bm + (col0 + wn * 64 + ml) * 1024 + quad * 8;

    f32x4 acc[4][4];
#pragma unroll
    for (int i = 0; i < 4; i++)
#pragma unroll
        for (int j = 0; j < 4; j++) acc[i][j] = (f32x4)(0.f);

    for (int k0 = 0; k0 < 1024; k0 += 32) {
        bf16x8 a[4], b[4];
#pragma unroll
        for (int i = 0; i < 4; i++) a[i] = *(const bf16x8*)(Abase + i * 16 * 1024 + k0);
#pragma unroll
        for (int j = 0; j < 4; j++) b[j] = *(const bf16x8*)(Bbase + j * 16 * 1024 + k0);
#pragma unroll
        for (int i = 0; i < 4; i++)
#pragma unroll
            for (int j = 0; j < 4; j++)
                acc[i][j] = __builtin_amdgcn_mfma_f32_16x16x32_bf16(a[i], b[j], acc[i][j], 0, 0, 0);
    }
    // C/D layout: col = lane&15, row = quad*4 + reg  [verified m89/m91]
#pragma unroll
    for (int i = 0; i < 4; i++)
#pragma unroll
        for (int j = 0; j < 4; j++) {
            int colg = col0 + wn * 64 + j * 16 + ml;
#pragma unroll
            for (int r = 0; r < 4; r++) {
                int row = arow + wm * 64 + i * 16 + quad * 4 + r;
                C[row * 1024 + colg] = acc[i][j][r];
            }
        }
}

// ---------------- fused score + softmax + context ---------------------------
// One block = one b, 4 consecutive q (t) values.
// score[j][k] = sum_u tanh(pq[j][u] + pk[k][u] + bias[u]) * v[u]
//             = Vsum - 2 * sum_u rcp(1 + exp2((pq+pk+bias)*2*log2e)) * v[u]
__global__ __launch_bounds__(256) void score_ctx(
    const float* __restrict__ pq, const float* __restrict__ pk,
    const float* __restrict__ keys, const float* __restrict__ bias,
    const float* __restrict__ v,
    float* __restrict__ out_ctx, float* __restrict__ out_sc) {
    __shared__ float pq2[4][1024];  // (pq+bias) pre-scaled by 2*log2(e)
    __shared__ float vs[1024];
    __shared__ float sc[4][128];
    const float C2 = 2.8853900817779268f;   // 2*log2(e)
    const float L2E = 1.4426950408889634f;
    int b = blockIdx.x;
    int q0 = blockIdx.y * 4;
    int tid = threadIdx.x;
    int w = tid >> 6, lane = tid & 63;

    for (int u = tid; u < 1024; u += 256) {
        vs[u] = v[u];
        float bb = bias[u];
#pragma unroll
        for (int j = 0; j < 4; j++)
            pq2[j][u] = (pq[((q0 + j) * 32 + b) * 1024 + u] + bb) * C2;
    }
    __syncthreads();
    float vsum = v[1024];

    for (int kk = 0; kk < 32; kk++) {
        int k = kk * 4 + w;
        const float* pkrow = pk + (k * 32 + b) * 1024;
        float a0 = 0.f, a1 = 0.f, a2 = 0.f, a3 = 0.f;
#pragma unroll
        for (int i = 0; i < 4; i++) {
            int u0 = i * 256 + lane * 4;
            float4 x4 = *(const float4*)(pkrow + u0);
            float4 v4 = *(const float4*)&vs[u0];
            float4 t0 = *(const float4*)&pq2[0][u0];
            float4 t1 = *(const float4*)&pq2[1][u0];
            float4 t2 = *(const float4*)&pq2[2][u0];
            float4 t3 = *(const float4*)&pq2[3][u0];
            float xs0 = x4.x * C2, xs1 = x4.y * C2, xs2 = x4.z * C2, xs3 = x4.w * C2;
#define TERM(acc, t, xs, vv) \
            acc = fmaf(__builtin_amdgcn_rcpf(1.f + __builtin_amdgcn_exp2f(xs + t)), vv, acc)
            TERM(a0, t0.x, xs0, v4.x); TERM(a1, t1.x, xs0, v4.x);
            TERM(a2, t2.x, xs0, v4.x); TERM(a3, t3.x, xs0, v4.x);
            TERM(a0, t0.y, xs1, v4.y); TERM(a1, t1.y, xs1, v4.y);
            TERM(a2, t2.y, xs1, v4.y); TERM(a3, t3.y, xs1, v4.y);
            TERM(a0, t0.z, xs2, v4.z); TERM(a1, t1.z, xs2, v4.z);
            TERM(a2, t2.z, xs2, v4.z); TERM(a3, t3.z, xs2, v4.z);
            TERM(a0, t0.w, xs3, v4.w); TERM(a1, t1.w, xs3, v4.w);
            TERM(a2, t2.w, xs3, v4.w); TERM(a3, t3.w, xs3, v4.w);
#undef TERM
        }
        a0 = wave_sum(a0); a1 = wave_sum(a1); a2 = wave_sum(a2); a3 = wave_sum(a3);
        if (lane == 0) {
            sc[0][k] = vsum - 2.f * a0;
            sc[1][k] = vsum - 2.f * a1;
            sc[2][k] = vsum - 2.f * a2;
            sc[3][k] = vsum - 2.f * a3;
        }
    }
    __syncthreads();

    // softmax over k (128) : wave w handles q-row j=w; lanes cover k and k+64
    {
        int j = w;
        float s1 = sc[j][lane], s2 = sc[j][lane + 64];
        float m = wave_max(fmaxf(s1, s2));
        float e1 = __builtin_amdgcn_exp2f((s1 - m) * L2E);
        float e2 = __builtin_amdgcn_exp2f((s2 - m) * L2E);
        float ssum = wave_sum(e1 + e2);
        float inv = __builtin_amdgcn_rcpf(ssum);
        float p1 = e1 * inv, p2 = e2 * inv;
        sc[j][lane] = p1; sc[j][lane + 64] = p2;
        float* o = out_sc + ((q0 + j) * 32 + b) * 128;
        o[lane] = p1; o[lane + 64] = p2;
    }
    __syncthreads();

    // context[j][n] = sum_k p[j][k] * keys[k][b][n]; thread owns 4 n's
    {
        int n0 = tid * 4;
        const float* kbase = keys + b * 1024 + n0;
        float c0x = 0, c0y = 0, c0z = 0, c0w = 0;
        float c1x = 0, c1y = 0, c1z = 0, c1w = 0;
        float c2x = 0, c2y = 0, c2z = 0, c2w = 0;
        float c3x = 0, c3y = 0, c3z = 0, c3w = 0;
        for (int k = 0; k < 128; k++) {
            float4 kv = *(const float4*)(kbase + k * 32768);
            float p0 = sc[0][k], p1 = sc[1][k], p2 = sc[2][k], p3 = sc[3][k];
            c0x = fmaf(p0, kv.x, c0x); c0y = fmaf(p0, kv.y, c0y);
            c0z = fmaf(p0, kv.z, c0z); c0w = fmaf(p0, kv.w, c0w);
            c1x = fmaf(p1, kv.x, c1x); c1y = fmaf(p1, kv.y, c1y);
            c1z = fmaf(p1, kv.z, c1z); c1w = fmaf(p1, kv.w, c1w);
            c2x = fmaf(p2, kv.x, c2x); c2y = fmaf(p2, kv.y, c2y);
            c2z = fmaf(p2, kv.z, c2z); c2w = fmaf(p2, kv.w, c2w);
            c3x = fmaf(p3, kv.x, c3x); c3y = fmaf(p3, kv.y, c3y);
            c3z = fmaf(p3, kv.z, c3z); c3w = fmaf(p3, kv.w, c3w);
        }
        float4 o;
        o.x = c0x; o.y = c0y; o.z = c0z; o.w = c0w;
        *(float4*)(out_ctx + ((q0 + 0) * 32 + b) * 1024 + n0) = o;
        o.x = c1x; o.y = c1y; o.z = c1z; o.w = c1w;
        *(float4*)(out_ctx + ((q0 + 1) * 32 + b) * 1024 + n0) = o;
        o.x = c2x; o.y = c2y; o.z = c2z; o.w = c2w;
        *(float4*)(out_ctx + ((q0 + 2) * 32 + b) * 1024 + n0) = o;
        o.x = c3x; o.y = c3y; o.z = c3z; o.w = c3w;
        *(float4*)(out_ctx + ((q0 + 3) * 32 + b) * 1024 + n0) = o;
    }
}

extern "C" void kernel_launch(void* const* d_in, const int* in_sizes, int n_in,
                              void* d_out, int out_size, void* d_ws, size_t ws_size,
                              hipStream_t stream) {
    const float* query = (const float*)d_in[0];
    const float* keys  = (const float*)d_in[1];
    const float* Wq    = (const float*)d_in[2];
    const float* Wk    = (const float*)d_in[3];
    const float* la    = (const float*)d_in[4];
    const float* ns    = (const float*)d_in[5];
    const float* bias  = (const float*)d_in[6];

    float* out_ctx = (float*)d_out;             // 64*32*1024
    float* out_sc  = (float*)d_out + 2097152;   // 64*32*128

    char* ws = (char*)d_ws;                     // needs ~40 MB
    float* v  = (float*)(ws);                   // 1025 floats
    float* pq = (float*)(ws + 8192);            // 8 MB
    float* pk = (float*)(ws + 8192 + 8388608);  // 16 MB
    unsigned short* qb  = (unsigned short*)(ws + 8192 + 8388608 + 16777216);
    unsigned short* kb  = qb + 2097152;
    unsigned short* wqb = kb + 4194304;
    unsigned short* wkb = wqb + 1048576;

    convert_kernel<<<8192, 256, 0, stream>>>(query, keys, Wq, Wk, qb, kb, wqb, wkb);
    vnorm_kernel<<<1, 256, 0, stream>>>(la, ns, v);
    proj_gemm<<<dim3(8, 48), 256, 0, stream>>>(qb, kb, wqb, wkb, pq, pk);
    score_ctx<<<dim3(32, 16), 256, 0, stream>>>(pq, pk, keys, bias, v, out_ctx, out_sc);
}

// Round 2
// 229.494 us; speedup vs baseline: 1.0006x; 1.0006x over previous
//
#include <hip/hip_runtime.h>
#include <stdint.h>

// Problem constants: t_q=64, t_k=128, b=32, n=1024
//   query (64,32,1024) f32 ; keys (128,32,1024) f32 ; Wq,Wk (1024,1024) f32
//   out0 = context (64,32,1024) f32 ; out1 = scores_softmax (64,32,128) f32

typedef __attribute__((ext_vector_type(8))) short bf16x8;
typedef __attribute__((ext_vector_type(4))) float f32x4;

#define C2_SCALE 2.8853900817779268f   // 2*log2(e)

__device__ __forceinline__ unsigned short f2bf(float x) {
    union { float f; uint32_t u; } v; v.f = x;
    uint32_t u = v.u;
    u += 0x7fffu + ((u >> 16) & 1u);   // round-to-nearest-even
    return (unsigned short)(u >> 16);
}

__device__ __forceinline__ float wave_sum(float x) {
#pragma unroll
    for (int off = 32; off; off >>= 1) x += __shfl_xor(x, off);
    return x;
}
__device__ __forceinline__ float wave_max(float x) {
#pragma unroll
    for (int off = 32; off; off >>= 1) x = fmaxf(x, __shfl_xor(x, off));
    return x;
}

// ---------------- f32 -> bf16 conversion of all 4 tensors -------------------
__global__ __launch_bounds__(256) void convert_kernel(
    const float* __restrict__ q, const float* __restrict__ k,
    const float* __restrict__ wq, const float* __restrict__ wk,
    unsigned short* __restrict__ qb, unsigned short* __restrict__ kb,
    unsigned short* __restrict__ wqb, unsigned short* __restrict__ wkb) {
    int idx = blockIdx.x * 256 + threadIdx.x;   // float4 index; 2097152 total
    int e = idx * 4;
    const float* src; unsigned short* dst; int off;
    if (e < 2097152)      { src = q;  dst = qb;  off = e; }
    else if (e < 6291456) { src = k;  dst = kb;  off = e - 2097152; }
    else if (e < 7340032) { src = wq; dst = wqb; off = e - 6291456; }
    else                  { src = wk; dst = wkb; off = e - 7340032; }
    float4 xv = *(const float4*)(src + off);
    ushort4 o;
    o.x = f2bf(xv.x); o.y = f2bf(xv.y); o.z = f2bf(xv.z); o.w = f2bf(xv.w);
    *(ushort4*)(dst + off) = o;
}

// ---------------- v = linear_att/||linear_att|| * ns; also sum(v) -----------
__global__ __launch_bounds__(256) void vnorm_kernel(
    const float* __restrict__ la, const float* __restrict__ ns,
    float* __restrict__ v) {
    __shared__ float red[4], red2[4];
    int tid = threadIdx.x, w = tid >> 6;
    float s = 0.f;
    for (int i = tid; i < 1024; i += 256) { float x = la[i]; s += x * x; }
    s = wave_sum(s);
    if ((tid & 63) == 0) red[w] = s;
    __syncthreads();
    float scale = rsqrtf(red[0] + red[1] + red[2] + red[3]) * ns[0];
    float vp = 0.f;
    for (int i = tid; i < 1024; i += 256) { float vv = la[i] * scale; v[i] = vv; vp += vv; }
    vp = wave_sum(vp);
    if ((tid & 63) == 0) red2[w] = vp;
    __syncthreads();
    if (tid == 0) v[1024] = red2[0] + red2[1] + red2[2] + red2[3];
}

// ---------------- combined projection GEMM: C = A * B^T (bf16 -> f32) -------
// rows 0..2047    -> pq = qb * wqb^T            (scale 1)
// rows 2048..6143 -> pk = kb * wkb^T * C2_SCALE (pre-scaled for score_ctx)
// Block tile 128 rows x 64 cols, 4 waves in 2x2, wave tile 64x32.
// Explicit ping-pong register prefetch (k-step 32, 2 in flight).
__global__ __launch_bounds__(256) void proj_gemm(
    const unsigned short* __restrict__ qb, const unsigned short* __restrict__ kb,
    const unsigned short* __restrict__ wqb, const unsigned short* __restrict__ wkb,
    float* __restrict__ pq, float* __restrict__ pk) {
    int col0 = blockIdx.x * 64;    // 16 col tiles
    int row0 = blockIdx.y * 128;   // 48 row tiles
    const unsigned short* A; const unsigned short* Bm; float* C; int arow; float scale;
    if (row0 < 2048) { A = qb; Bm = wqb; C = pq; arow = row0;        scale = 1.0f; }
    else             { A = kb; Bm = wkb; C = pk; arow = row0 - 2048; scale = C2_SCALE; }
    int tid = threadIdx.x;
    int w = tid >> 6, lane = tid & 63;
    int wm = w >> 1, wn = w & 1;          // 2x2 waves
    int ml = lane & 15, quad = lane >> 4;

    const unsigned short* Abase = A + (arow + wm * 64 + ml) * 1024 + quad * 8;
    const unsigned short* Bbase = Bm + (col0 + wn * 32 + ml) * 1024 + quad * 8;

    f32x4 acc[4][2];
#pragma unroll
    for (int i = 0; i < 4; i++)
#pragma unroll
        for (int j = 0; j < 2; j++) acc[i][j] = (f32x4)(0.f);

    bf16x8 a0[4], b0[2], a1[4], b1[2];
#define LOADF(af, bf, kk) do {                                         \
        _Pragma("unroll")                                              \
        for (int i = 0; i < 4; i++) af[i] = *(const bf16x8*)(Abase + i * 16 * 1024 + (kk)); \
        _Pragma("unroll")                                              \
        for (int j = 0; j < 2; j++) bf[j] = *(const bf16x8*)(Bbase + j * 16 * 1024 + (kk)); \
    } while (0)
#define MFMAF(af, bf) do {                                             \
        _Pragma("unroll")                                              \
        for (int i = 0; i < 4; i++)                                    \
            _Pragma("unroll")                                          \
            for (int j = 0; j < 2; j++)                                \
                acc[i][j] = __builtin_amdgcn_mfma_f32_16x16x32_bf16(af[i], bf[j], acc[i][j], 0, 0, 0); \
    } while (0)

    LOADF(a0, b0, 0);
    for (int k0 = 0; k0 < 1024 - 64; k0 += 64) {
        LOADF(a1, b1, k0 + 32);
        MFMAF(a0, b0);
        LOADF(a0, b0, k0 + 64);
        MFMAF(a1, b1);
    }
    LOADF(a1, b1, 992);
    MFMAF(a0, b0);
    MFMAF(a1, b1);
#undef LOADF
#undef MFMAF

    // C/D layout: col = lane&15, row = quad*4 + reg
#pragma unroll
    for (int i = 0; i < 4; i++)
#pragma unroll
        for (int j = 0; j < 2; j++) {
            int colg = col0 + wn * 32 + j * 16 + ml;
#pragma unroll
            for (int r = 0; r < 4; r++) {
                int row = arow + wm * 64 + i * 16 + quad * 4 + r;
                C[row * 1024 + colg] = acc[i][j][r] * scale;
            }
        }
}

// ---------------- fused score + softmax + context ---------------------------
// One block = one b, 4 consecutive q (t) values; 512 threads = 8 waves.
// score[j][k] = sum_u tanh(pq[j][u] + pk[k][u] + bias[u]) * v[u]
//             = Vsum - 2 * sum_u rcp(1 + exp2((pq+pk+bias)*2*log2e)) * v[u]
// pk arrives pre-scaled by 2*log2e from proj_gemm.
__global__ __launch_bounds__(512) void score_ctx(
    const float* __restrict__ pq, const float* __restrict__ pk2,
    const float* __restrict__ keys, const float* __restrict__ bias,
    const float* __restrict__ v,
    float* __restrict__ out_ctx, float* __restrict__ out_sc) {
    __shared__ float pq2[4][1024];  // (pq+bias) pre-scaled by 2*log2(e)
    __shared__ float vs[1024];
    __shared__ float sc[4][128];
    const float L2E = 1.4426950408889634f;
    int b = blockIdx.x;
    int q0 = blockIdx.y * 4;
    int tid = threadIdx.x;
    int w = tid >> 6, lane = tid & 63;   // w in 0..7

    for (int u = tid; u < 1024; u += 512) {
        vs[u] = v[u];
        float bb = bias[u];
#pragma unroll
        for (int j = 0; j < 4; j++)
            pq2[j][u] = (pq[((q0 + j) * 32 + b) * 1024 + u] + bb) * C2_SCALE;
    }
    __syncthreads();
    float vsum = v[1024];

    for (int kk = 0; kk < 16; kk++) {
        int k = kk * 8 + w;
        const float* pkrow = pk2 + (k * 32 + b) * 1024;
        float a0 = 0.f, a1 = 0.f, a2 = 0.f, a3 = 0.f;
#pragma unroll
        for (int i = 0; i < 4; i++) {
            int u0 = i * 256 + lane * 4;
            float4 x4 = *(const float4*)(pkrow + u0);   // already * C2
            float4 v4 = *(const float4*)&vs[u0];
            float4 t0 = *(const float4*)&pq2[0][u0];
            float4 t1 = *(const float4*)&pq2[1][u0];
            float4 t2 = *(const float4*)&pq2[2][u0];
            float4 t3 = *(const float4*)&pq2[3][u0];
#define TERM(acc, t, xs, vv) \
            acc = fmaf(__builtin_amdgcn_rcpf(1.f + __builtin_amdgcn_exp2f(xs + t)), vv, acc)
            TERM(a0, t0.x, x4.x, v4.x); TERM(a1, t1.x, x4.x, v4.x);
            TERM(a2, t2.x, x4.x, v4.x); TERM(a3, t3.x, x4.x, v4.x);
            TERM(a0, t0.y, x4.y, v4.y); TERM(a1, t1.y, x4.y, v4.y);
            TERM(a2, t2.y, x4.y, v4.y); TERM(a3, t3.y, x4.y, v4.y);
            TERM(a0, t0.z, x4.z, v4.z); TERM(a1, t1.z, x4.z, v4.z);
            TERM(a2, t2.z, x4.z, v4.z); TERM(a3, t3.z, x4.z, v4.z);
            TERM(a0, t0.w, x4.w, v4.w); TERM(a1, t1.w, x4.w, v4.w);
            TERM(a2, t2.w, x4.w, v4.w); TERM(a3, t3.w, x4.w, v4.w);
#undef TERM
        }
        a0 = wave_sum(a0); a1 = wave_sum(a1); a2 = wave_sum(a2); a3 = wave_sum(a3);
        if (lane == 0) {
            sc[0][k] = vsum - 2.f * a0;
            sc[1][k] = vsum - 2.f * a1;
            sc[2][k] = vsum - 2.f * a2;
            sc[3][k] = vsum - 2.f * a3;
        }
    }
    __syncthreads();

    // softmax over k (128): waves 0..3 handle q-row j=w; lanes cover k, k+64
    if (w < 4) {
        int j = w;
        float s1 = sc[j][lane], s2 = sc[j][lane + 64];
        float m = wave_max(fmaxf(s1, s2));
        float e1 = __builtin_amdgcn_exp2f((s1 - m) * L2E);
        float e2 = __builtin_amdgcn_exp2f((s2 - m) * L2E);
        float ssum = wave_sum(e1 + e2);
        float inv = __builtin_amdgcn_rcpf(ssum);
        float p1 = e1 * inv, p2 = e2 * inv;
        sc[j][lane] = p1; sc[j][lane + 64] = p2;
        float* o = out_sc + ((q0 + j) * 32 + b) * 128;
        o[lane] = p1; o[lane + 64] = p2;
    }
    __syncthreads();

    // context[j][n] = sum_k p[j][k] * keys[k][b][n]; thread owns 2 n's, 4 rows
    {
        int n0 = tid * 2;
        const float* kbase = keys + b * 1024 + n0;
        float c0x = 0, c0y = 0, c1x = 0, c1y = 0;
        float c2x = 0, c2y = 0, c3x = 0, c3y = 0;
        for (int k = 0; k < 128; k++) {
            float2 kv = *(const float2*)(kbase + k * 32768);
            float p0 = sc[0][k], p1 = sc[1][k], p2 = sc[2][k], p3 = sc[3][k];
            c0x = fmaf(p0, kv.x, c0x); c0y = fmaf(p0, kv.y, c0y);
            c1x = fmaf(p1, kv.x, c1x); c1y = fmaf(p1, kv.y, c1y);
            c2x = fmaf(p2, kv.x, c2x); c2y = fmaf(p2, kv.y, c2y);
            c3x = fmaf(p3, kv.x, c3x); c3y = fmaf(p3, kv.y, c3y);
        }
        float2 o;
        o.x = c0x; o.y = c0y; *(float2*)(out_ctx + ((q0 + 0) * 32 + b) * 1024 + n0) = o;
        o.x = c1x; o.y = c1y; *(float2*)(out_ctx + ((q0 + 1) * 32 + b) * 1024 + n0) = o;
        o.x = c2x; o.y = c2y; *(float2*)(out_ctx + ((q0 + 2) * 32 + b) * 1024 + n0) = o;
        o.x = c3x; o.y = c3y; *(float2*)(out_ctx + ((q0 + 3) * 32 + b) * 1024 + n0) = o;
    }
}

extern "C" void kernel_launch(void* const* d_in, const int* in_sizes, int n_in,
                              void* d_out, int out_size, void* d_ws, size_t ws_size,
                              hipStream_t stream) {
    const float* query = (const float*)d_in[0];
    const float* keys  = (const float*)d_in[1];
    const float* Wq    = (const float*)d_in[2];
    const float* Wk    = (const float*)d_in[3];
    const float* la    = (const float*)d_in[4];
    const float* ns    = (const float*)d_in[5];
    const float* bias  = (const float*)d_in[6];

    float* out_ctx = (float*)d_out;             // 64*32*1024
    float* out_sc  = (float*)d_out + 2097152;   // 64*32*128

    char* ws = (char*)d_ws;                     // needs ~42 MB
    float* v  = (float*)(ws);                   // 1025 floats
    float* pq = (float*)(ws + 8192);            // 8 MB
    float* pk = (float*)(ws + 8192 + 8388608);  // 16 MB
    unsigned short* qb  = (unsigned short*)(ws + 8192 + 8388608 + 16777216);
    unsigned short* kb  = qb + 2097152;
    unsigned short* wqb = kb + 4194304;
    unsigned short* wkb = wqb + 1048576;

    vnorm_kernel<<<1, 256, 0, stream>>>(la, ns, v);
    convert_kernel<<<8192, 256, 0, stream>>>(query, keys, Wq, Wk, qb, kb, wqb, wkb);
    proj_gemm<<<dim3(16, 48), 256, 0, stream>>>(qb, kb, wqb, wkb, pq, pk);
    score_ctx<<<dim3(32, 16), 512, 0, stream>>>(pq, pk, keys, bias, v, out_ctx, out_sc);
}